// Round 1
// baseline (745.554 us; speedup 1.0000x reference)
//
#include <hip/hip_runtime.h>
#include <hip/hip_bf16.h>
#include <cstdint>
#include <cstddef>

// MFMA fragment types (per cdna_hip_programming.md §3, compile-verified layout)
typedef __attribute__((ext_vector_type(8))) short bf16x8;   // 8 bf16 in 4 VGPRs
typedef __attribute__((ext_vector_type(4))) float f32x4;    // 4 fp32 acc

static __device__ __forceinline__ unsigned short f2bf(float f) {
    union { float f; unsigned u; } v; v.f = f;
    unsigned r = (v.u + 0x7fffu + ((v.u >> 16) & 1u)) >> 16;
    return (unsigned short)r;
}

// ---------------------------------------------------------------------------
// K1: per-row L2 norm; write normalized bf16 copy, optional fp32 identity
// copy, optional transposed (unnormalized) bf16 copy. C == 256, block = 64.
// ---------------------------------------------------------------------------
__global__ __launch_bounds__(64) void rownorm_kernel(
    const float* __restrict__ in, unsigned short* __restrict__ nrm,
    float* __restrict__ cpy, unsigned short* __restrict__ trans,
    int transStride)
{
    const int row  = blockIdx.x;
    const int lane = threadIdx.x;
    const float4 v = *(const float4*)(in + (size_t)row * 256 + lane * 4);
    float ss = v.x * v.x + v.y * v.y + v.z * v.z + v.w * v.w;
    #pragma unroll
    for (int off = 32; off > 0; off >>= 1) ss += __shfl_xor(ss, off);
    const float rn = rsqrtf(ss);   // norms ~16, far above EPS=1e-8

    ushort4 o;
    o.x = f2bf(v.x * rn); o.y = f2bf(v.y * rn);
    o.z = f2bf(v.z * rn); o.w = f2bf(v.w * rn);
    *(ushort4*)(nrm + (size_t)row * 256 + lane * 4) = o;

    if (cpy) *(float4*)(cpy + (size_t)row * 256 + lane * 4) = v;

    if (trans) {
        const int c = lane * 4;
        trans[(size_t)(c + 0) * transStride + row] = f2bf(v.x);
        trans[(size_t)(c + 1) * transStride + row] = f2bf(v.y);
        trans[(size_t)(c + 2) * transStride + row] = f2bf(v.z);
        trans[(size_t)(c + 3) * transStride + row] = f2bf(v.w);
    }
}

// ---------------------------------------------------------------------------
// K2: logits GEMM. C[m][s] = sum_c A[m][c]*B[s][c], A:[M,256] B:[S,256] bf16.
// 128x128 tile, 256 threads = 4 waves (2x2 of 64x64), BK=32, K=256.
// ---------------------------------------------------------------------------
__global__ __launch_bounds__(256) void gemm_logits_kernel(
    const unsigned short* __restrict__ A,
    const unsigned short* __restrict__ B,
    float* __restrict__ Cout, int S)
{
    __shared__ unsigned short As[128 * 32];
    __shared__ unsigned short Bs[128 * 32];
    const int row0 = blockIdx.y * 128;
    const int col0 = blockIdx.x * 128;
    const int tid  = threadIdx.x;
    const int wave = tid >> 6, lane = tid & 63;
    const int wm = (wave >> 1) * 64, wn = (wave & 1) * 64;
    const int quad = lane >> 4, r16 = lane & 15;

    f32x4 acc[4][4];
    #pragma unroll
    for (int i = 0; i < 4; i++)
        #pragma unroll
        for (int j = 0; j < 4; j++) acc[i][j] = 0.f;

    for (int k0 = 0; k0 < 256; k0 += 32) {
        #pragma unroll
        for (int it = 0; it < 2; ++it) {
            const int c = tid + it * 256;          // 512 chunks of 8 bf16
            const int r = c >> 2, cj = c & 3;
            *(uint4*)(&As[r * 32 + cj * 8]) =
                *(const uint4*)(A + (size_t)(row0 + r) * 256 + k0 + cj * 8);
            *(uint4*)(&Bs[r * 32 + cj * 8]) =
                *(const uint4*)(B + (size_t)(col0 + r) * 256 + k0 + cj * 8);
        }
        __syncthreads();
        bf16x8 af[4], bfr[4];
        #pragma unroll
        for (int i = 0; i < 4; i++) {
            af[i]  = *(const bf16x8*)(&As[(wm + i * 16 + r16) * 32 + quad * 8]);
            bfr[i] = *(const bf16x8*)(&Bs[(wn + i * 16 + r16) * 32 + quad * 8]);
        }
        #pragma unroll
        for (int i = 0; i < 4; i++)
            #pragma unroll
            for (int j = 0; j < 4; j++)
                acc[i][j] = __builtin_amdgcn_mfma_f32_16x16x32_bf16(
                    af[i], bfr[j], acc[i][j], 0, 0, 0);
        __syncthreads();
    }

    #pragma unroll
    for (int i = 0; i < 4; i++) {
        #pragma unroll
        for (int j = 0; j < 4; j++) {
            const int r  = row0 + wm + i * 16 + quad * 4;  // C/D: row=quad*4+reg
            const int cc = col0 + wn + j * 16 + r16;       //      col=lane&15
            #pragma unroll
            for (int rr = 0; rr < 4; rr++)
                Cout[(size_t)(r + rr) * S + cc] = acc[i][j][rr];
        }
    }
}

// ---------------------------------------------------------------------------
// K3: in-place log_softmax over rows of [rows, 4096]. 1 block (256 thr) / row.
// ---------------------------------------------------------------------------
__global__ __launch_bounds__(256) void logsoftmax_kernel(float* __restrict__ buf)
{
    __shared__ float red[4];
    const int row = blockIdx.x;
    float* rp = buf + (size_t)row * 4096;
    const int t = threadIdx.x;
    const int wave = t >> 6;

    float4 x[4];
    #pragma unroll
    for (int i = 0; i < 4; i++) x[i] = ((const float4*)rp)[t + i * 256];

    float m = -INFINITY;
    #pragma unroll
    for (int i = 0; i < 4; i++) {
        m = fmaxf(m, fmaxf(fmaxf(x[i].x, x[i].y), fmaxf(x[i].z, x[i].w)));
    }
    #pragma unroll
    for (int off = 32; off > 0; off >>= 1) m = fmaxf(m, __shfl_xor(m, off));
    if ((t & 63) == 0) red[wave] = m;
    __syncthreads();
    m = fmaxf(fmaxf(red[0], red[1]), fmaxf(red[2], red[3]));
    __syncthreads();

    float s = 0.f;
    #pragma unroll
    for (int i = 0; i < 4; i++) {
        s += __expf(x[i].x - m); s += __expf(x[i].y - m);
        s += __expf(x[i].z - m); s += __expf(x[i].w - m);
    }
    #pragma unroll
    for (int off = 32; off > 0; off >>= 1) s += __shfl_xor(s, off);
    if ((t & 63) == 0) red[wave] = s;
    __syncthreads();
    s = red[0] + red[1] + red[2] + red[3];
    const float lse = m + __logf(s);

    #pragma unroll
    for (int i = 0; i < 4; i++) {
        x[i].x -= lse; x[i].y -= lse; x[i].z -= lse; x[i].w -= lse;
        ((float4*)rp)[t + i * 256] = x[i];
    }
}

// ---------------------------------------------------------------------------
// K4: recall GEMM. out[m][c] = sum_s exp(Plog[m][s]) * svm[s][c].
// BT = svm transposed bf16 [256, 4096]. Tile 64x256, 4 waves (64x64 each),
// BK=32, K=4096.
// ---------------------------------------------------------------------------
__global__ __launch_bounds__(256) void gemm_recall_kernel(
    const float* __restrict__ Plog,
    const unsigned short* __restrict__ BT,
    float* __restrict__ out)
{
    __shared__ unsigned short As[64 * 32];
    __shared__ unsigned short Bs[256 * 32];
    const int row0 = blockIdx.x * 64;
    const int tid  = threadIdx.x;
    const int wave = tid >> 6, lane = tid & 63;
    const int wn = wave * 64;
    const int quad = lane >> 4, r16 = lane & 15;

    f32x4 acc[4][4];
    #pragma unroll
    for (int i = 0; i < 4; i++)
        #pragma unroll
        for (int j = 0; j < 4; j++) acc[i][j] = 0.f;

    for (int k0 = 0; k0 < 4096; k0 += 32) {
        // A: 64 rows x 32 k of exp(Plog) -> bf16. 512 float4 chunks.
        #pragma unroll
        for (int it = 0; it < 2; ++it) {
            const int c = tid + it * 256;
            const int r = c >> 3, cj = c & 7;
            const float4 v = *(const float4*)(Plog + (size_t)(row0 + r) * 4096 + k0 + cj * 4);
            ushort4 o;
            o.x = f2bf(__expf(v.x)); o.y = f2bf(__expf(v.y));
            o.z = f2bf(__expf(v.z)); o.w = f2bf(__expf(v.w));
            *(ushort4*)(&As[r * 32 + cj * 4]) = o;
        }
        // B: 256 rows x 32 k of BT. 1024 chunks of 8 bf16.
        #pragma unroll
        for (int it = 0; it < 4; ++it) {
            const int c = tid + it * 256;
            const int r = c >> 2, cj = c & 3;
            *(uint4*)(&Bs[r * 32 + cj * 8]) =
                *(const uint4*)(BT + (size_t)r * 4096 + k0 + cj * 8);
        }
        __syncthreads();
        bf16x8 af[4], bfr[4];
        #pragma unroll
        for (int i = 0; i < 4; i++) {
            af[i]  = *(const bf16x8*)(&As[(i * 16 + r16) * 32 + quad * 8]);
            bfr[i] = *(const bf16x8*)(&Bs[(wn + i * 16 + r16) * 32 + quad * 8]);
        }
        #pragma unroll
        for (int i = 0; i < 4; i++)
            #pragma unroll
            for (int j = 0; j < 4; j++)
                acc[i][j] = __builtin_amdgcn_mfma_f32_16x16x32_bf16(
                    af[i], bfr[j], acc[i][j], 0, 0, 0);
        __syncthreads();
    }

    #pragma unroll
    for (int i = 0; i < 4; i++) {
        #pragma unroll
        for (int j = 0; j < 4; j++) {
            const int r  = row0 + i * 16 + quad * 4;
            const int cc = wn + j * 16 + r16;
            #pragma unroll
            for (int rr = 0; rr < 4; rr++)
                out[(size_t)(r + rr) * 256 + cc] = acc[i][j][rr];
        }
    }
}

// ---------------------------------------------------------------------------
extern "C" void kernel_launch(void* const* d_in, const int* in_sizes, int n_in,
                              void* d_out, int out_size, void* d_ws, size_t ws_size,
                              hipStream_t stream) {
    const float* face   = (const float*)d_in[0];   // [8192,256]
    const float* speech = (const float*)d_in[1];   // [8192,256]
    const float* svm    = (const float*)d_in[2];   // [4096,256]
    const float* fkm    = (const float*)d_in[3];   // [4096,256]

    const int N = 8192, S = 4096, C = 256;
    float* out = (float*)d_out;
    float* out_speech  = out;                          // [N,C]
    float* out_srecall = out + (size_t)N * C;          // [N,C]
    float* out_face    = out + 2 * (size_t)N * C;      // [N,C]
    float* out_frecall = out + 3 * (size_t)N * C;      // [N,C]
    float* out_slog    = out + 4 * (size_t)N * C;      // [N,S]
    float* out_flog    = out_slog + (size_t)N * S;     // [N,S]

    unsigned short* speech_n = (unsigned short*)d_ws;            // N*C bf16
    unsigned short* face_n   = speech_n + (size_t)N * C;         // N*C
    unsigned short* svm_n    = face_n + (size_t)N * C;           // S*C
    unsigned short* fkm_n    = svm_n + (size_t)S * C;            // S*C
    unsigned short* svmT     = fkm_n + (size_t)S * C;            // C x S (unnormalized)

    rownorm_kernel<<<N, 64, 0, stream>>>(speech, speech_n, out_speech, nullptr, 0);
    rownorm_kernel<<<N, 64, 0, stream>>>(face,   face_n,   out_face,   nullptr, 0);
    rownorm_kernel<<<S, 64, 0, stream>>>(svm,    svm_n,    nullptr,    svmT,    S);
    rownorm_kernel<<<S, 64, 0, stream>>>(fkm,    fkm_n,    nullptr,    nullptr, 0);

    dim3 g2(S / 128, N / 128);
    gemm_logits_kernel<<<g2, 256, 0, stream>>>(speech_n, svm_n, out_slog, S);
    gemm_logits_kernel<<<g2, 256, 0, stream>>>(face_n,   fkm_n, out_flog, S);

    logsoftmax_kernel<<<N, 256, 0, stream>>>(out_slog);
    logsoftmax_kernel<<<N, 256, 0, stream>>>(out_flog);

    gemm_recall_kernel<<<N / 64, 256, 0, stream>>>(out_slog, svmT, out_srecall);
    gemm_recall_kernel<<<N / 64, 256, 0, stream>>>(out_flog, svmT, out_frecall);
}

// Round 2
// 544.740 us; speedup vs baseline: 1.3686x; 1.3686x over previous
//
#include <hip/hip_runtime.h>
#include <hip/hip_bf16.h>
#include <cstdint>
#include <cstddef>

typedef __attribute__((ext_vector_type(8))) short bf16x8;   // 8 bf16 in 4 VGPRs
typedef __attribute__((ext_vector_type(4))) float f32x4;    // 4 fp32 acc

static __device__ __forceinline__ unsigned short f2bf(float f) {
    union { float f; unsigned u; } v; v.f = f;
    return (unsigned short)((v.u + 0x7fffu + ((v.u >> 16) & 1u)) >> 16);
}
static __device__ __forceinline__ float bf2f(unsigned short h) {
    union { unsigned u; float f; } v; v.u = ((unsigned)h) << 16;
    return v.f;
}

#define NC 2097152      // 8192*256
#define SC 1048576      // 4096*256
#define NS 33554432     // 8192*4096
#define SPLITS 4

// ---------------------------------------------------------------------------
// K1: per-row L2 norm for all 4 inputs in one launch. grid (8192, 4), 64 thr.
// which: 0=speech(copy out) 1=face(copy out) 2=svm(also transpose) 3=fkm.
// ---------------------------------------------------------------------------
__global__ __launch_bounds__(64) void rownorm_kernel(
    const float* __restrict__ face, const float* __restrict__ speech,
    const float* __restrict__ svm, const float* __restrict__ fkm,
    unsigned short* __restrict__ face_n, unsigned short* __restrict__ speech_n,
    unsigned short* __restrict__ svm_n, unsigned short* __restrict__ fkm_n,
    float* __restrict__ out_face, float* __restrict__ out_speech,
    unsigned short* __restrict__ svmT)
{
    const int which = blockIdx.y;
    const int row   = blockIdx.x;
    if (which >= 2 && row >= 4096) return;

    const float* in; unsigned short* nrm; float* cpy = nullptr; bool tr = false;
    if (which == 0)      { in = speech; nrm = speech_n; cpy = out_speech; }
    else if (which == 1) { in = face;   nrm = face_n;   cpy = out_face; }
    else if (which == 2) { in = svm;    nrm = svm_n;    tr = true; }
    else                 { in = fkm;    nrm = fkm_n; }

    const int lane = threadIdx.x;
    const float4 v = *(const float4*)(in + (size_t)row * 256 + lane * 4);
    float ss = v.x * v.x + v.y * v.y + v.z * v.z + v.w * v.w;
    #pragma unroll
    for (int off = 32; off > 0; off >>= 1) ss += __shfl_xor(ss, off);
    const float rn = rsqrtf(ss);   // norms ~8-16, far above EPS=1e-8

    ushort4 o;
    o.x = f2bf(v.x * rn); o.y = f2bf(v.y * rn);
    o.z = f2bf(v.z * rn); o.w = f2bf(v.w * rn);
    *(ushort4*)(nrm + (size_t)row * 256 + lane * 4) = o;

    if (cpy) *(float4*)(cpy + (size_t)row * 256 + lane * 4) = v;

    if (tr) {   // svmT[c][s] = svm[s][c], bf16, unnormalized, stride 4096
        const int c = lane * 4;
        svmT[(size_t)(c + 0) * 4096 + row] = f2bf(v.x);
        svmT[(size_t)(c + 1) * 4096 + row] = f2bf(v.y);
        svmT[(size_t)(c + 2) * 4096 + row] = f2bf(v.z);
        svmT[(size_t)(c + 3) * 4096 + row] = f2bf(v.w);
    }
}

// ---------------------------------------------------------------------------
// K2: logits GEMM, batched over sides (z). L[m][s] = sum_c A[m][c]*B[s][c].
// 128x128 tile, 256 thr = 4 waves (2x2 of 64x64), BK=32, K=256.
// Writes bf16 logits to ws.
// ---------------------------------------------------------------------------
__global__ __launch_bounds__(256) void gemm_logits_kernel(
    const unsigned short* __restrict__ speech_n,
    const unsigned short* __restrict__ face_n,
    const unsigned short* __restrict__ svm_n,
    const unsigned short* __restrict__ fkm_n,
    unsigned short* __restrict__ logits)   // [2][8192][4096]
{
    __shared__ unsigned short As[128 * 32];
    __shared__ unsigned short Bs[128 * 32];
    const int side = blockIdx.z;
    const unsigned short* A = side ? face_n : speech_n;
    const unsigned short* B = side ? fkm_n  : svm_n;
    unsigned short* Lg = logits + ((size_t)side * NS);

    const int row0 = blockIdx.y * 128;
    const int col0 = blockIdx.x * 128;
    const int tid  = threadIdx.x;
    const int wave = tid >> 6, lane = tid & 63;
    const int wm = (wave >> 1) * 64, wn = (wave & 1) * 64;
    const int quad = lane >> 4, r16 = lane & 15;

    f32x4 acc[4][4];
    #pragma unroll
    for (int i = 0; i < 4; i++)
        #pragma unroll
        for (int j = 0; j < 4; j++) acc[i][j] = 0.f;

    for (int k0 = 0; k0 < 256; k0 += 32) {
        #pragma unroll
        for (int it = 0; it < 2; ++it) {
            const int c = tid + it * 256;          // 512 chunks of 8 bf16
            const int r = c >> 2, cj = c & 3;
            *(uint4*)(&As[r * 32 + cj * 8]) =
                *(const uint4*)(A + (size_t)(row0 + r) * 256 + k0 + cj * 8);
            *(uint4*)(&Bs[r * 32 + cj * 8]) =
                *(const uint4*)(B + (size_t)(col0 + r) * 256 + k0 + cj * 8);
        }
        __syncthreads();
        bf16x8 af[4], bfr[4];
        #pragma unroll
        for (int i = 0; i < 4; i++) {
            af[i]  = *(const bf16x8*)(&As[(wm + i * 16 + r16) * 32 + quad * 8]);
            bfr[i] = *(const bf16x8*)(&Bs[(wn + i * 16 + r16) * 32 + quad * 8]);
        }
        #pragma unroll
        for (int i = 0; i < 4; i++)
            #pragma unroll
            for (int j = 0; j < 4; j++)
                acc[i][j] = __builtin_amdgcn_mfma_f32_16x16x32_bf16(
                    af[i], bfr[j], acc[i][j], 0, 0, 0);
        __syncthreads();
    }

    #pragma unroll
    for (int i = 0; i < 4; i++) {
        #pragma unroll
        for (int j = 0; j < 4; j++) {
            const int r  = row0 + wm + i * 16 + quad * 4;  // C/D: row=quad*4+reg
            const int cc = col0 + wn + j * 16 + r16;       //      col=lane&15
            #pragma unroll
            for (int rr = 0; rr < 4; rr++)
                Lg[(size_t)(r + rr) * 4096 + cc] = f2bf(acc[i][j][rr]);
        }
    }
}

// ---------------------------------------------------------------------------
// K3: softmax. Logits in [-1,1] -> no max subtraction needed.
// Reads bf16 logits, writes fp32 log_softmax to out, bf16 probs P to ws.
// grid 2*8192 blocks, 256 thr; each block one row of 4096.
// ---------------------------------------------------------------------------
__global__ __launch_bounds__(256) void softmax_kernel(
    const unsigned short* __restrict__ logits,  // [2][8192][4096]
    unsigned short* __restrict__ P,             // [2][8192][4096]
    float* __restrict__ out_slog, float* __restrict__ out_flog)
{
    __shared__ float red[4];
    const int b = blockIdx.x;
    const int side = b >> 13, row = b & 8191;
    const size_t off = (size_t)side * NS + ((size_t)row << 12);
    const unsigned short* lp = logits + off;
    unsigned short* pp = P + off;
    float* op = (side ? out_flog : out_slog) + ((size_t)row << 12);
    const int t = threadIdx.x;

    float x[16], e[16];
    float s = 0.f;
    #pragma unroll
    for (int i = 0; i < 2; i++) {
        const int j = t + i * 256;                  // chunk 0..511 of 8 bf16
        unsigned short vv[8];
        *(uint4*)vv = *(const uint4*)(lp + (size_t)j * 8);
        #pragma unroll
        for (int k = 0; k < 8; k++) {
            const float xv = bf2f(vv[k]);
            x[i * 8 + k] = xv;
            const float ev = __expf(xv);
            e[i * 8 + k] = ev;
            s += ev;
        }
    }
    #pragma unroll
    for (int o = 32; o > 0; o >>= 1) s += __shfl_xor(s, o);
    if ((t & 63) == 0) red[t >> 6] = s;
    __syncthreads();
    s = red[0] + red[1] + red[2] + red[3];
    const float lse = __logf(s);
    const float inv = 1.0f / s;

    #pragma unroll
    for (int i = 0; i < 2; i++) {
        const int j = t + i * 256;
        float4 o0, o1;
        o0.x = x[i*8+0] - lse; o0.y = x[i*8+1] - lse;
        o0.z = x[i*8+2] - lse; o0.w = x[i*8+3] - lse;
        o1.x = x[i*8+4] - lse; o1.y = x[i*8+5] - lse;
        o1.z = x[i*8+6] - lse; o1.w = x[i*8+7] - lse;
        ((float4*)op)[j * 2]     = o0;
        ((float4*)op)[j * 2 + 1] = o1;
        unsigned short pv[8];
        #pragma unroll
        for (int k = 0; k < 8; k++) pv[k] = f2bf(e[i * 8 + k] * inv);
        *(uint4*)(pp + (size_t)j * 8) = *(uint4*)pv;
    }
}

// ---------------------------------------------------------------------------
// K4: recall GEMM, split-K. out[m][c] = sum_s P[m][s]*svm[s][c].
// grid (128 mtiles, SPLITS, 2 sides), 256 thr. Tile 64x256, BK=32.
// Pure bf16 staging (no exp). Writes fp32 partials to ws.
// ---------------------------------------------------------------------------
__global__ __launch_bounds__(256) void gemm_recall_kernel(
    const unsigned short* __restrict__ P,    // [2][8192][4096]
    const unsigned short* __restrict__ BT,   // [256][4096] = svm^T bf16
    float* __restrict__ part)                // [2][SPLITS][8192][256]
{
    __shared__ unsigned short As[64 * 32];
    __shared__ unsigned short Bs[256 * 32];
    const int row0  = blockIdx.x * 64;
    const int split = blockIdx.y;
    const int side  = blockIdx.z;
    const unsigned short* A = P + (size_t)side * NS;
    float* outp = part + (((size_t)side * SPLITS + split) << 21);  // *2097152
    const int kbase = split * (4096 / SPLITS);

    const int tid  = threadIdx.x;
    const int wave = tid >> 6, lane = tid & 63;
    const int wn = wave * 64;
    const int quad = lane >> 4, r16 = lane & 15;

    f32x4 acc[4][4];
    #pragma unroll
    for (int i = 0; i < 4; i++)
        #pragma unroll
        for (int j = 0; j < 4; j++) acc[i][j] = 0.f;

    for (int k0 = kbase; k0 < kbase + 4096 / SPLITS; k0 += 32) {
        // A: 64x32 bf16 = 256 chunks of 8; one per thread.
        *(uint4*)(&As[(tid >> 2) * 32 + (tid & 3) * 8]) =
            *(const uint4*)(A + (size_t)(row0 + (tid >> 2)) * 4096 + k0 + (tid & 3) * 8);
        // B: 256x32 bf16 = 1024 chunks.
        #pragma unroll
        for (int it = 0; it < 4; ++it) {
            const int c = tid + it * 256, r = c >> 2, cj = c & 3;
            *(uint4*)(&Bs[r * 32 + cj * 8]) =
                *(const uint4*)(BT + (size_t)r * 4096 + k0 + cj * 8);
        }
        __syncthreads();
        bf16x8 af[4], bfr[4];
        #pragma unroll
        for (int i = 0; i < 4; i++) {
            af[i]  = *(const bf16x8*)(&As[(i * 16 + r16) * 32 + quad * 8]);
            bfr[i] = *(const bf16x8*)(&Bs[(wn + i * 16 + r16) * 32 + quad * 8]);
        }
        #pragma unroll
        for (int i = 0; i < 4; i++)
            #pragma unroll
            for (int j = 0; j < 4; j++)
                acc[i][j] = __builtin_amdgcn_mfma_f32_16x16x32_bf16(
                    af[i], bfr[j], acc[i][j], 0, 0, 0);
        __syncthreads();
    }

    #pragma unroll
    for (int i = 0; i < 4; i++) {
        #pragma unroll
        for (int j = 0; j < 4; j++) {
            const int r  = row0 + i * 16 + quad * 4;
            const int cc = wn + j * 16 + r16;
            #pragma unroll
            for (int rr = 0; rr < 4; rr++)
                outp[(size_t)(r + rr) * 256 + cc] = acc[i][j][rr];
        }
    }
}

// ---------------------------------------------------------------------------
// K5: reduce split-K partials -> recall outputs. grid 4096 blocks x 256 thr.
// ---------------------------------------------------------------------------
__global__ __launch_bounds__(256) void reduce_kernel(
    const float* __restrict__ part,
    float* __restrict__ out_srecall, float* __restrict__ out_frecall)
{
    const int idx = blockIdx.x * 256 + threadIdx.x;   // float4 index
    const int side = idx >> 19;                       // 524288 float4 per side
    const int off = idx & ((1 << 19) - 1);
    const float4* p = (const float4*)(part + ((size_t)side * SPLITS << 21));
    float4 s = p[off];
    #pragma unroll
    for (int sp = 1; sp < SPLITS; sp++) {
        const float4 v = p[off + (size_t)sp * (1 << 19)];
        s.x += v.x; s.y += v.y; s.z += v.z; s.w += v.w;
    }
    float4* o = (float4*)(side ? out_frecall : out_srecall);
    o[off] = s;
}

// ---------------------------------------------------------------------------
extern "C" void kernel_launch(void* const* d_in, const int* in_sizes, int n_in,
                              void* d_out, int out_size, void* d_ws, size_t ws_size,
                              hipStream_t stream) {
    const float* face   = (const float*)d_in[0];   // [8192,256]
    const float* speech = (const float*)d_in[1];   // [8192,256]
    const float* svm    = (const float*)d_in[2];   // [4096,256]
    const float* fkm    = (const float*)d_in[3];   // [4096,256]

    const int N = 8192, S = 4096, C = 256;
    float* out = (float*)d_out;
    float* out_speech  = out;                          // [N,C]
    float* out_srecall = out + (size_t)N * C;          // [N,C]
    float* out_face    = out + 2 * (size_t)N * C;      // [N,C]
    float* out_frecall = out + 3 * (size_t)N * C;      // [N,C]
    float* out_slog    = out + 4 * (size_t)N * C;      // [N,S]
    float* out_flog    = out_slog + (size_t)N * S;     // [N,S]

    // ws layout (evidence: harness poisons ~1152 MiB -> ws is plentiful; we use ~334 MB)
    unsigned short* wsu = (unsigned short*)d_ws;
    unsigned short* speech_n = wsu;                      // NC
    unsigned short* face_n   = speech_n + NC;            // NC
    unsigned short* svm_n    = face_n + NC;              // SC
    unsigned short* fkm_n    = svm_n + SC;               // SC
    unsigned short* svmT     = fkm_n + SC;               // SC ([256][4096])
    unsigned short* logits   = svmT + SC;                // 2*NS
    unsigned short* Pws      = logits + 2 * (size_t)NS;  // 2*NS
    float* part = (float*)(Pws + 2 * (size_t)NS);        // 2*SPLITS*N*C fp32

    dim3 g1(N, 4);
    rownorm_kernel<<<g1, 64, 0, stream>>>(face, speech, svm, fkm,
                                          face_n, speech_n, svm_n, fkm_n,
                                          out_face, out_speech, svmT);

    dim3 g2(S / 128, N / 128, 2);
    gemm_logits_kernel<<<g2, 256, 0, stream>>>(speech_n, face_n, svm_n, fkm_n, logits);

    softmax_kernel<<<2 * N, 256, 0, stream>>>(logits, Pws, out_slog, out_flog);

    dim3 g4(N / 64, SPLITS, 2);
    gemm_recall_kernel<<<g4, 256, 0, stream>>>(Pws, svmT, part);

    reduce_kernel<<<2 * (N * C / 4) / 256, 256, 0, stream>>>(part, out_srecall, out_frecall);
}